// Round 1
// baseline (309.246 us; speedup 1.0000x reference)
//
#include <hip/hip_runtime.h>
#include <math.h>

#define B_DIM 128
#define SEQ   3000
#define FDIM  64
#define NSTEP 999          // (SEQ - 3) / 3 sequential scan steps
#define U     9            // steps per prefetch group
#define NG    111          // 111 * 9 = 999

// exact gelu: 0.5*x*(1+erf(x/sqrt(2)))
__device__ __forceinline__ float gelu_f(float v) {
    return 0.5f * v * (1.0f + erff(v * 0.70710678118654752440f));
}

__global__ __launch_bounds__(64, 1) void scan_kernel(
    const float* __restrict__ x,
    const float* __restrict__ w,
    const float* __restrict__ bias,
    float* __restrict__ out)
{
    const int b = blockIdx.x;      // 128 blocks, one b per block
    const int f = threadIdx.x;     // 64 lanes = all f of this b

    // 3x3 weights + bias (wave-uniform -> SGPRs)
    const float w00 = w[0], w01 = w[1], w02 = w[2];
    const float w10 = w[3], w11 = w[4], w12 = w[5];
    const float w20 = w[6], w21 = w[7], w22 = w[8];
    const float b0 = bias[0], b1 = bias[1], b2 = bias[2];

    const float* __restrict__ xp = x   + (size_t)b * (SEQ * FDIM) + f;
    float*       __restrict__ op = out + (size_t)b * (SEQ * FDIM) + f;

    // head: copy + init state
    float s0 = xp[0 * FDIM], s1 = xp[1 * FDIM], s2 = xp[2 * FDIM];
    op[0 * FDIM] = s0; op[1 * FDIM] = s1; op[2 * FDIM] = s2;

    const float* xc = xp + 3 * FDIM;   // next group to PREFETCH (after prologue load)
    float*       oc = op + 3 * FDIM;   // next group to write

    float A[3 * U], Bf[3 * U];

    // prologue: load group 0 into A
    #pragma unroll
    for (int i = 0; i < 3 * U; ++i) A[i] = xc[i * FDIM];
    xc += 3 * U * FDIM;                // now points at group 1

    // prefetch next group into buf (27 independent loads, ~1 group of compute ahead)
    #define PREFETCH(buf)                                        \
        {                                                        \
            _Pragma("unroll")                                    \
            for (int i = 0; i < 3 * U; ++i) buf[i] = xc[i * FDIM]; \
            xc += 3 * U * FDIM;                                  \
        }

    // compute U steps from buf, store outputs
    #define COMPUTE(buf)                                                        \
        {                                                                       \
            _Pragma("unroll")                                                   \
            for (int k = 0; k < U; ++k) {                                       \
                float a0 = fmaf(s2, w02, fmaf(s1, w01, s0 * w00)) + b0;         \
                float a1 = fmaf(s2, w12, fmaf(s1, w11, s0 * w10)) + b1;         \
                float a2 = fmaf(s2, w22, fmaf(s1, w21, s0 * w20)) + b2;         \
                s0 = gelu_f(a0) + buf[3 * k + 0];                               \
                s1 = gelu_f(a1) + buf[3 * k + 1];                               \
                s2 = gelu_f(a2) + buf[3 * k + 2];                               \
                oc[(3 * k + 0) * FDIM] = s0;                                    \
                oc[(3 * k + 1) * FDIM] = s1;                                    \
                oc[(3 * k + 2) * FDIM] = s2;                                    \
            }                                                                   \
            oc += 3 * U * FDIM;                                                 \
        }

    // 55 double-groups: prefetch groups 1..110, compute groups 0..109.
    // Ping-pong is unrolled 2x so all buffer indices are compile-time constants
    // (runtime-indexed register arrays spill to scratch).
    #pragma unroll 1
    for (int j = 0; j < (NG - 1) / 2; ++j) {
        PREFETCH(Bf)
        COMPUTE(A)
        PREFETCH(A)
        COMPUTE(Bf)
    }
    // tail: group 110 (already prefetched into A)
    COMPUTE(A)

    #undef PREFETCH
    #undef COMPUTE
}

extern "C" void kernel_launch(void* const* d_in, const int* in_sizes, int n_in,
                              void* d_out, int out_size, void* d_ws, size_t ws_size,
                              hipStream_t stream) {
    const float* x    = (const float*)d_in[0];
    const float* w    = (const float*)d_in[1];
    const float* bias = (const float*)d_in[2];
    float* out        = (float*)d_out;

    hipLaunchKernelGGL(scan_kernel, dim3(B_DIM), dim3(FDIM), 0, stream,
                       x, w, bias, out);
}

// Round 2
// 150.081 us; speedup vs baseline: 2.0605x; 2.0605x over previous
//
#include <hip/hip_runtime.h>
#include <math.h>

#define B_DIM 128
#define SEQ   3000
#define FDIM  64
#define NSTEP 999          // (SEQ - 3) / 3 sequential scan steps
#define U     9            // steps per prefetch group
#define NG    111          // 111 * 9 = 999

// Branchless gelu, exact-erf formulation:
//   gelu(x) = relu(x) - 0.5*|x|*erfc(|x|/sqrt(2))      (valid for all x)
//   erfc(u) via Abramowitz-Stegun 7.1.26 (|abs err| <= 1.5e-7 on erf, u>=0):
//   erfc(u) = (a1 t + a2 t^2 + a3 t^3 + a4 t^4 + a5 t^5) * exp(-u^2),
//   t = 1/(1 + p u)
__device__ __forceinline__ float gelu_f(float v) {
    const float ISQRT2 = 0.70710678118654752440f;
    float u = fabsf(v) * ISQRT2;
    float d = fmaf(0.3275911f, u, 1.0f);
    float r = __builtin_amdgcn_rcpf(d);
    r = r * fmaf(-d, r, 2.0f);                 // one Newton step: ~0.5 ulp recip
    float p = fmaf(1.061405429f, r, -1.453152027f);
    p = fmaf(p, r, 1.421413741f);
    p = fmaf(p, r, -0.284496736f);
    p = fmaf(p, r, 0.254829592f);
    p = p * r;                                 // P(t)*t
    float ex = __expf(-u * u);                 // v_exp-based; flushes to 0 for big u
    float er = p * ex;                         // erfc(u)
    float relu = fmaxf(v, 0.0f);
    return fmaf(-0.5f * fabsf(v), er, relu);
}

__global__ __launch_bounds__(64, 1) void scan_kernel(
    const float* __restrict__ x,
    const float* __restrict__ w,
    const float* __restrict__ bias,
    float* __restrict__ out)
{
    const int b = blockIdx.x;      // 128 blocks, one b per block
    const int f = threadIdx.x;     // 64 lanes = all f of this b

    // 3x3 weights + bias (wave-uniform -> SGPRs)
    const float w00 = w[0], w01 = w[1], w02 = w[2];
    const float w10 = w[3], w11 = w[4], w12 = w[5];
    const float w20 = w[6], w21 = w[7], w22 = w[8];
    const float b0 = bias[0], b1 = bias[1], b2 = bias[2];

    const float* __restrict__ xp = x   + (size_t)b * (SEQ * FDIM) + f;
    float*       __restrict__ op = out + (size_t)b * (SEQ * FDIM) + f;

    // head: copy + init state
    float s0 = xp[0 * FDIM], s1 = xp[1 * FDIM], s2 = xp[2 * FDIM];
    op[0 * FDIM] = s0; op[1 * FDIM] = s1; op[2 * FDIM] = s2;

    const float* xc = xp + 3 * FDIM;   // next group to PREFETCH (after prologue load)
    float*       oc = op + 3 * FDIM;   // next group to write

    float A[3 * U], Bf[3 * U];

    // prologue: load group 0 into A
    #pragma unroll
    for (int i = 0; i < 3 * U; ++i) A[i] = xc[i * FDIM];
    xc += 3 * U * FDIM;                // now points at group 1

    // prefetch next group into buf (27 independent loads, ~1 group of compute ahead)
    #define PREFETCH(buf)                                        \
        {                                                        \
            _Pragma("unroll")                                    \
            for (int i = 0; i < 3 * U; ++i) buf[i] = xc[i * FDIM]; \
            xc += 3 * U * FDIM;                                  \
        }

    // compute U steps from buf, store outputs
    #define COMPUTE(buf)                                                        \
        {                                                                       \
            _Pragma("unroll")                                                   \
            for (int k = 0; k < U; ++k) {                                       \
                float a0 = fmaf(s2, w02, fmaf(s1, w01, fmaf(s0, w00, b0)));     \
                float a1 = fmaf(s2, w12, fmaf(s1, w11, fmaf(s0, w10, b1)));     \
                float a2 = fmaf(s2, w22, fmaf(s1, w21, fmaf(s0, w20, b2)));     \
                s0 = gelu_f(a0) + buf[3 * k + 0];                               \
                s1 = gelu_f(a1) + buf[3 * k + 1];                               \
                s2 = gelu_f(a2) + buf[3 * k + 2];                               \
                oc[(3 * k + 0) * FDIM] = s0;                                    \
                oc[(3 * k + 1) * FDIM] = s1;                                    \
                oc[(3 * k + 2) * FDIM] = s2;                                    \
            }                                                                   \
            oc += 3 * U * FDIM;                                                 \
        }

    // 55 double-groups: prefetch groups 1..110, compute groups 0..109.
    // Ping-pong is unrolled 2x so all buffer indices are compile-time constants
    // (runtime-indexed register arrays spill to scratch).
    #pragma unroll 1
    for (int j = 0; j < (NG - 1) / 2; ++j) {
        PREFETCH(Bf)
        COMPUTE(A)
        PREFETCH(A)
        COMPUTE(Bf)
    }
    // tail: group 110 (already prefetched into A)
    COMPUTE(A)

    #undef PREFETCH
    #undef COMPUTE
}

extern "C" void kernel_launch(void* const* d_in, const int* in_sizes, int n_in,
                              void* d_out, int out_size, void* d_ws, size_t ws_size,
                              hipStream_t stream) {
    const float* x    = (const float*)d_in[0];
    const float* w    = (const float*)d_in[1];
    const float* bias = (const float*)d_in[2];
    float* out        = (float*)d_out;

    hipLaunchKernelGGL(scan_kernel, dim3(B_DIM), dim3(FDIM), 0, stream,
                       x, w, bias, out);
}

// Round 3
// 147.581 us; speedup vs baseline: 2.0954x; 1.0169x over previous
//
#include <hip/hip_runtime.h>
#include <math.h>

#define B_DIM 128
#define SEQ   3000
#define FDIM  64
// 999 sequential steps = 111 groups x 9 steps; prefetch runs 2 groups ahead.

// Branchless gelu, exact-erf formulation:
//   gelu(x) = relu(x) - 0.5*|x|*erfc(|x|/sqrt(2))      (valid for all x)
//   erfc via Abramowitz-Stegun 7.1.26 (|abs err| <= 1.5e-7), t = 1/(1+p*u)
__device__ __forceinline__ float gelu_f(float v) {
    const float ISQRT2 = 0.70710678118654752440f;
    float u = fabsf(v) * ISQRT2;
    float d = fmaf(0.3275911f, u, 1.0f);
    float r = __builtin_amdgcn_rcpf(d);
    r = r * fmaf(-d, r, 2.0f);                 // one Newton step
    float p = fmaf(1.061405429f, r, -1.453152027f);
    p = fmaf(p, r, 1.421413741f);
    p = fmaf(p, r, -0.284496736f);
    p = fmaf(p, r, 0.254829592f);
    p = p * r;                                 // P(t)*t
    float ex = __expf(-u * u);
    float er = p * ex;                         // erfc(u)
    float relu = fmaxf(v, 0.0f);
    return fmaf(-0.5f * fabsf(v), er, relu);
}

// 27 named scalars per buffer: nothing is indexable -> nothing can be demoted
// to scratch, and loads become loop-carried (cannot be sunk to their use).
#define DECL27(p) float p##0,p##1,p##2,p##3,p##4,p##5,p##6,p##7,p##8,p##9,    \
    p##10,p##11,p##12,p##13,p##14,p##15,p##16,p##17,p##18,p##19,p##20,p##21,  \
    p##22,p##23,p##24,p##25,p##26

#define BUF(p) p##0,p##1,p##2,p##3,p##4,p##5,p##6,p##7,p##8,p##9,p##10,p##11, \
    p##12,p##13,p##14,p##15,p##16,p##17,p##18,p##19,p##20,p##21,p##22,p##23,  \
    p##24,p##25,p##26

#define LOADG_IMPL(y0,y1,y2,y3,y4,y5,y6,y7,y8,y9,y10,y11,y12,y13,y14,y15,y16, \
                   y17,y18,y19,y20,y21,y22,y23,y24,y25,y26)                    \
    do {                                                                       \
        y0  = xc[ 0*FDIM]; y1  = xc[ 1*FDIM]; y2  = xc[ 2*FDIM];              \
        y3  = xc[ 3*FDIM]; y4  = xc[ 4*FDIM]; y5  = xc[ 5*FDIM];              \
        y6  = xc[ 6*FDIM]; y7  = xc[ 7*FDIM]; y8  = xc[ 8*FDIM];              \
        y9  = xc[ 9*FDIM]; y10 = xc[10*FDIM]; y11 = xc[11*FDIM];              \
        y12 = xc[12*FDIM]; y13 = xc[13*FDIM]; y14 = xc[14*FDIM];              \
        y15 = xc[15*FDIM]; y16 = xc[16*FDIM]; y17 = xc[17*FDIM];              \
        y18 = xc[18*FDIM]; y19 = xc[19*FDIM]; y20 = xc[20*FDIM];              \
        y21 = xc[21*FDIM]; y22 = xc[22*FDIM]; y23 = xc[23*FDIM];              \
        y24 = xc[24*FDIM]; y25 = xc[25*FDIM]; y26 = xc[26*FDIM];              \
        xc += 27 * FDIM;                                                       \
    } while (0)
#define LOADG(...) LOADG_IMPL(__VA_ARGS__)

// one scan step; k is the compile-time step index within the group
#define STEP(k, u0, u1, u2)                                                    \
    do {                                                                       \
        float a0 = fmaf(s2, w02, fmaf(s1, w01, fmaf(s0, w00, q0)));            \
        float a1 = fmaf(s2, w12, fmaf(s1, w11, fmaf(s0, w10, q1)));            \
        float a2 = fmaf(s2, w22, fmaf(s1, w21, fmaf(s0, w20, q2)));            \
        s0 = gelu_f(a0) + u0;                                                  \
        s1 = gelu_f(a1) + u1;                                                  \
        s2 = gelu_f(a2) + u2;                                                  \
        oc[(3*(k)+0)*FDIM] = s0;                                               \
        oc[(3*(k)+1)*FDIM] = s1;                                               \
        oc[(3*(k)+2)*FDIM] = s2;                                               \
    } while (0)

#define COMPUTE_IMPL(y0,y1,y2,y3,y4,y5,y6,y7,y8,y9,y10,y11,y12,y13,y14,y15,   \
                     y16,y17,y18,y19,y20,y21,y22,y23,y24,y25,y26)              \
    do {                                                                       \
        STEP(0, y0,  y1,  y2 );                                                \
        STEP(1, y3,  y4,  y5 );                                                \
        STEP(2, y6,  y7,  y8 );                                                \
        STEP(3, y9,  y10, y11);                                                \
        STEP(4, y12, y13, y14);                                                \
        STEP(5, y15, y16, y17);                                                \
        STEP(6, y18, y19, y20);                                                \
        STEP(7, y21, y22, y23);                                                \
        STEP(8, y24, y25, y26);                                                \
        oc += 27 * FDIM;                                                       \
    } while (0)
#define COMPUTE(...) COMPUTE_IMPL(__VA_ARGS__)

__global__ __launch_bounds__(64, 1) void scan_kernel(
    const float* __restrict__ x,
    const float* __restrict__ w,
    const float* __restrict__ bias,
    float* __restrict__ out)
{
    const int b = blockIdx.x;      // 128 blocks, one b per block
    const int f = threadIdx.x;     // 64 lanes = all f of this b

    const float w00 = w[0], w01 = w[1], w02 = w[2];
    const float w10 = w[3], w11 = w[4], w12 = w[5];
    const float w20 = w[6], w21 = w[7], w22 = w[8];
    const float q0 = bias[0], q1 = bias[1], q2 = bias[2];

    const float* __restrict__ xp = x   + (size_t)b * (SEQ * FDIM) + f;
    float*       __restrict__ op = out + (size_t)b * (SEQ * FDIM) + f;

    float s0 = xp[0 * FDIM], s1 = xp[1 * FDIM], s2 = xp[2 * FDIM];
    op[0 * FDIM] = s0; op[1 * FDIM] = s1; op[2 * FDIM] = s2;

    const float* xc = xp + 3 * FDIM;
    float*       oc = op + 3 * FDIM;

    DECL27(A); DECL27(B); DECL27(C);

    // prologue: groups 0,1 in flight
    LOADG(BUF(A));                 // g0
    LOADG(BUF(B));                 // g1

    // steady state: prefetch distance = 2 groups (~18 steps of compute)
    // 36 iterations x 3 groups = groups 0..107 computed, 2..109 loaded
    #pragma unroll 1
    for (int t = 0; t < 36; ++t) {
        LOADG(BUF(C)); COMPUTE(BUF(A));   // load g(3t+2), compute g(3t)
        LOADG(BUF(A)); COMPUTE(BUF(B));   // load g(3t+3), compute g(3t+1)
        LOADG(BUF(B)); COMPUTE(BUF(C));   // load g(3t+4), compute g(3t+2)
    }

    // epilogue: g108 in A, g109 in B; load and compute g110
    LOADG(BUF(C));                 // g110
    COMPUTE(BUF(A));               // g108
    COMPUTE(BUF(B));               // g109
    COMPUTE(BUF(C));               // g110
}

extern "C" void kernel_launch(void* const* d_in, const int* in_sizes, int n_in,
                              void* d_out, int out_size, void* d_ws, size_t ws_size,
                              hipStream_t stream) {
    const float* x    = (const float*)d_in[0];
    const float* w    = (const float*)d_in[1];
    const float* bias = (const float*)d_in[2];
    float* out        = (float*)d_out;

    hipLaunchKernelGGL(scan_kernel, dim3(B_DIM), dim3(FDIM), 0, stream,
                       x, w, bias, out);
}